// Round 3
// baseline (267.050 us; speedup 1.0000x reference)
//
#include <hip/hip_runtime.h>
#include <cstdint>

typedef __bf16 bf16;
typedef __bf16 bf16x8 __attribute__((ext_vector_type(8)));
typedef float f32x4 __attribute__((ext_vector_type(4)));

#define MFMA16(a, b, c) __builtin_amdgcn_mfma_f32_16x16x32_bf16((a), (b), (c), 0, 0, 0)
#define GLDS16(g, l)                                                         \
  __builtin_amdgcn_global_load_lds(                                          \
      (__attribute__((address_space(1))) void*)(g),                          \
      (__attribute__((address_space(3))) void*)(l), 16, 0, 0)

// ---- one prep kernel: 6 weight transposes + x/ctx/img casts (grid z=11) ----
__global__ void prep_all(const float* __restrict__ Wq, const float* __restrict__ Wo,
                         const float* __restrict__ Wk, const float* __restrict__ Wv,
                         const float* __restrict__ Wkip, const float* __restrict__ Wvip,
                         bf16* __restrict__ WqT, bf16* __restrict__ WoT,
                         bf16* __restrict__ WkT, bf16* __restrict__ WvT,
                         bf16* __restrict__ WkipT, bf16* __restrict__ WvipT,
                         const float* __restrict__ x, bf16* __restrict__ xb,
                         const float* __restrict__ ctx, bf16* __restrict__ ctxb,
                         const float* __restrict__ img, bf16* __restrict__ imgb) {
  const int z = blockIdx.z;
  const int tx = threadIdx.x, ty = threadIdx.y;
  if (z < 6) {
    const float* src = (z == 0) ? Wq : (z == 1) ? Wo : (z == 2) ? Wk
                      : (z == 3) ? Wv : (z == 4) ? Wkip : Wvip;
    bf16* dst = (z == 0) ? WqT : (z == 1) ? WoT : (z == 2) ? WkT
               : (z == 3) ? WvT : (z == 4) ? WkipT : WvipT;
    const int K = (z < 2) ? 1280 : 2048;
    const int N = 1280;
    __shared__ float t[32][33];
    const int bx = blockIdx.x * 32, by = blockIdx.y * 32;
    if (by >= K) return;
#pragma unroll
    for (int i = 0; i < 32; i += 8)
      t[ty + i][tx] = src[(long)(by + ty + i) * N + bx + tx];
    __syncthreads();
#pragma unroll
    for (int i = 0; i < 32; i += 8)
      dst[(long)(bx + ty + i) * K + by + tx] = (bf16)t[tx][ty + i];
    return;
  }
  const int tid = ty * 32 + tx;
  const int bid = blockIdx.y * 40 + blockIdx.x;  // 0..2559
  const float* s;
  bf16* d;
  long base;
  if (z < 10) {  // x: 4 slices x 2560 blocks x 2048 elems = 20971520 exact
    base = (((long)(z - 6) * 2560 + bid) * 256 + tid) * 8;
    s = x; d = xb;
  } else if (bid < 308) {  // ctx: 308*2048 = 630784 exact
    base = ((long)bid * 256 + tid) * 8;
    s = ctx; d = ctxb;
  } else if (bid < 372) {  // img: 64*2048 = 131072 exact
    base = ((long)(bid - 308) * 256 + tid) * 8;
    s = img; d = imgb;
  } else {
    return;
  }
  float4 a = *(const float4*)(s + base);
  float4 b = *(const float4*)(s + base + 4);
  bf16x8 o;
  o[0] = (bf16)a.x; o[1] = (bf16)a.y; o[2] = (bf16)a.z; o[3] = (bf16)a.w;
  o[4] = (bf16)b.x; o[5] = (bf16)b.y; o[6] = (bf16)b.z; o[7] = (bf16)b.w;
  *(bf16x8*)(d + base) = o;
}

// ====== 256x256 quad-buffered GEMM, r1-proven schedule: C = A @ Bt^T ======
// 512 thr = 8 waves (2Mx4N), per-wave 128x64, BK=32.  4 slots x 32KB = 128KB
// LDS (1 WG/CU).  Depth-3 prefetch, 1 barrier + 1 lgkm(0) per K-step,
// reads for tile t+1 issued BEFORE tile t's MFMA clusters (r1 mechanism —
// r2's per-phase read->lgkm->MFMA serialization was the regression).
// Iter t (slot slc=t%4): lgkm(0) [all 12 READS(t) done] ; stage(t+3 ->
//   (t+3)%4) ; vmcnt(8) [outstanding t+1,t+2,t+3=12 -> oldest 4 = t+1
//   landed] ; barrier ; bN+aLoN(t+1) [8 reads] ; MFMA-lo(t) [16] ;
//   aHiN(t+1) [4 reads] ; MFMA-hi(t) [16].
// A-frag rotation (a0..a3 quartets) + B ping-pong keeps peak frag regs ~96;
// acc[8][4] (128) -> AGPR.  WAR stage(t+3)->slot(t-1)%4: tile-(t-1) reads
// drained at every wave's top-of-(t-1) lgkm(0) < barrier(t-1) < any wave's
// iter-t stage (r1 proof, slot-mod-4).  RAW: vmcnt(8)+barrier covers t+1
// cross-wave.  NT even (40 or 64).  Swizzle identical to r1 (conflicts=0).
template <bool OUT_BF16, bool HAS_BIAS>
__device__ __forceinline__ void gemm256_core(const bf16* A, const bf16* Bt,
                                             void* Cp, const float* bias,
                                             int K, int N, int tm, int tn,
                                             int Mlim) {
  __shared__ bf16 Al[4][256 * 32];
  __shared__ bf16 Bl[4][256 * 32];
  const int tid = threadIdx.x;
  const int wave = tid >> 6, lane = tid & 63;
  const int g = lane >> 4, l16 = lane & 15;
  const int wr = wave >> 2, wc = wave & 3;  // wave grid 2x4

  // staging (r1 pattern): one glds = 16 rows x 32 cols (64B/row, 4 lanes/row)
  const int sr = lane >> 2;
  const int sc = ((lane & 3) ^ ((lane >> 3) & 3)) * 8;  // source pre-swizzle
  const bf16* ga0 = A + (long)(tm + wave * 16 + sr) * K + sc;   // rows 0..127
  const bf16* ga1 = ga0 + (long)128 * K;                        // rows 128..255
  const bf16* gb0 = Bt + (long)(tn + wave * 16 + sr) * K + sc;
  const bf16* gb1 = gb0 + (long)128 * K;

  f32x4 acc[8][4] = {};
  const int rsw = (g ^ ((l16 >> 1) & 3)) * 8;  // read-side swizzle (r1)
  const int paOfs = (wr * 128 + l16) * 32 + rsw;
  const int pbOfs = (wc * 64 + l16) * 32 + rsw;

  const int NT = K >> 5;  // 40 or 64 (even, >=4)

#define STAGE_TILE(t_, b_)                        \
  {                                               \
    const int kt_ = (t_) << 5;                    \
    GLDS16(ga0 + kt_, &Al[b_][wave * 512]);       \
    GLDS16(ga1 + kt_, &Al[b_][(wave + 8) * 512]); \
    GLDS16(gb0 + kt_, &Bl[b_][wave * 512]);       \
    GLDS16(gb1 + kt_, &Bl[b_][(wave + 8) * 512]); \
  }

  // prologue: tiles 0,1,2 -> slots 0,1,2; tile0 landed; reads(0) issued
  STAGE_TILE(0, 0);
  STAGE_TILE(1, 1);
  STAGE_TILE(2, 2);
  asm volatile("s_waitcnt vmcnt(8)" ::: "memory");  // 12 issued, oldest 4 = t0
  asm volatile("s_barrier" ::: "memory");
  bf16x8 a0[4], a1[4], a2[4], a3[4], b0[4], b1[4];
  {
    const bf16* pb_ = &Bl[0][pbOfs];
#pragma unroll
    for (int j = 0; j < 4; j++) b0[j] = *(const bf16x8*)(pb_ + j * 512);
    const bf16* pa_ = &Al[0][paOfs];
#pragma unroll
    for (int i = 0; i < 4; i++) a0[i] = *(const bf16x8*)(pa_ + i * 512);
#pragma unroll
    for (int i = 0; i < 4; i++) a1[i] = *(const bf16x8*)(pa_ + 2048 + i * 512);
  }
  int slc = 0;

#define GEMM_ITER(t_, aLoC, aHiC, bC, aLoN, aHiN, bN)                    \
  {                                                                      \
    asm volatile("s_waitcnt lgkmcnt(0)" ::: "memory");                   \
    __builtin_amdgcn_sched_barrier(0);                                   \
    if ((t_) + 3 < NT) {                                                 \
      STAGE_TILE((t_) + 3, (slc + 3) & 3);                               \
      asm volatile("s_waitcnt vmcnt(8)" ::: "memory");                   \
    } else if ((t_) + 1 < NT) {                                          \
      asm volatile("s_waitcnt vmcnt(0)" ::: "memory");                   \
    }                                                                    \
    asm volatile("s_barrier" ::: "memory");                              \
    const int srd_ = (slc + 1) & 3;                                      \
    if ((t_) + 1 < NT) {                                                 \
      const bf16* pb_ = &Bl[srd_][pbOfs];                                \
      _Pragma("unroll") for (int j_ = 0; j_ < 4; j_++)                   \
          bN[j_] = *(const bf16x8*)(pb_ + j_ * 512);                     \
      const bf16* pa_ = &Al[srd_][paOfs];                                \
      _Pragma("unroll") for (int i_ = 0; i_ < 4; i_++)                   \
          aLoN[i_] = *(const bf16x8*)(pa_ + i_ * 512);                   \
    }                                                                    \
    __builtin_amdgcn_sched_barrier(0);                                   \
    __builtin_amdgcn_s_setprio(1);                                       \
    _Pragma("unroll") for (int i_ = 0; i_ < 4; i_++)                     \
        _Pragma("unroll") for (int j_ = 0; j_ < 4; j_++)                 \
            acc[i_][j_] = MFMA16(aLoC[i_], bC[j_], acc[i_][j_]);         \
    __builtin_amdgcn_s_setprio(0);                                       \
    __builtin_amdgcn_sched_barrier(0);                                   \
    if ((t_) + 1 < NT) {                                                 \
      const bf16* pa_ = &Al[srd_][paOfs + 2048];                         \
      _Pragma("unroll") for (int i_ = 0; i_ < 4; i_++)                   \
          aHiN[i_] = *(const bf16x8*)(pa_ + i_ * 512);                   \
    }                                                                    \
    __builtin_amdgcn_sched_barrier(0);                                   \
    __builtin_amdgcn_s_setprio(1);                                       \
    _Pragma("unroll") for (int i_ = 0; i_ < 4; i_++)                     \
        _Pragma("unroll") for (int j_ = 0; j_ < 4; j_++)                 \
            acc[4 + i_][j_] = MFMA16(aHiC[i_], bC[j_], acc[4 + i_][j_]); \
    __builtin_amdgcn_s_setprio(0);                                       \
    slc = srd_;                                                          \
  }

  for (int t = 0; t < NT; t += 2) {
    GEMM_ITER(t, a0, a1, b0, a2, a3, b1);
    GEMM_ITER(t + 1, a2, a3, b1, a0, a1, b0);
  }
#undef GEMM_ITER
#undef STAGE_TILE

#pragma unroll
  for (int mi = 0; mi < 8; ++mi) {
#pragma unroll
    for (int nj = 0; nj < 4; ++nj) {
      const int col = tn + wc * 64 + nj * 16 + l16;
      float bv = 0.f;
      if (HAS_BIAS) bv = bias[col];
#pragma unroll
      for (int r = 0; r < 4; ++r) {
        const long row = (long)tm + wr * 128 + mi * 16 + g * 4 + r;
        if (row < Mlim) {
          float v = acc[mi][nj][r] + bv;
          if (OUT_BF16)
            ((bf16*)Cp)[row * N + col] = (bf16)v;
          else
            ((float*)Cp)[row * N + col] = v;
        }
      }
    }
  }
}

// ---- grid 350: 30 small-GEMM tiles FIRST (K=2048, longest), then Q-proj
// (320 tiles, XCD supertile: chunk q&7, 8 tm x 5 tn walked tn-fastest).
// Small tiles: Mlim store-guard; A-row overreads land in next ws buffer. ----
__global__ __launch_bounds__(512, 2) void gemm_qproj_small(
    const bf16* __restrict__ xb, const bf16* __restrict__ WqT,
    bf16* __restrict__ qb, const bf16* __restrict__ ctxb,
    const bf16* __restrict__ imgb, const bf16* __restrict__ WkT,
    const bf16* __restrict__ WvT, const bf16* __restrict__ WkipT,
    const bf16* __restrict__ WvipT, bf16* __restrict__ kb,
    bf16* __restrict__ vb, bf16* __restrict__ ipkb, bf16* __restrict__ ipvb) {
  const int i = blockIdx.x;
  const bf16 *A, *Bt;
  bf16* C;
  int K, tm, tn, Mlim;
  if (i >= 30) {
    const int q = i - 30;      // 0..319
    const int local = q >> 3;  // 0..39
    A = xb; Bt = WqT; C = qb; K = 1280; Mlim = 1 << 30;
    tm = ((q & 7) * 8 + local / 5) * 256;
    tn = (local % 5) * 256;
  } else {
    // 0..9 K-proj (2Mx5N), 10..19 V-proj, 20..24 ipK, 25..29 ipV
    int z, bx, by;
    if (i < 20) {
      z = i / 10;
      const int r = i % 10;
      bx = r / 5; by = r % 5;
    } else {
      z = 2 + (i - 20) / 5;
      bx = 0; by = (i - 20) % 5;
    }
    A = (z < 2) ? ctxb : imgb;
    Bt = (z == 0) ? WkT : (z == 1) ? WvT : (z == 2) ? WkipT : WvipT;
    C = (z == 0) ? kb : (z == 1) ? vb : (z == 2) ? ipkb : ipvb;
    K = 2048;
    tm = bx * 256;
    tn = by * 256;
    Mlim = (z < 2) ? 384 : 128;  // buffer row counts (valid rows 308 / 64)
  }
  gemm256_core<true, false>(A, Bt, C, nullptr, K, 1280, tm, tn, Mlim);
}

// ---- out-proj, grid 320, same supertile map ----
__global__ __launch_bounds__(512, 2) void gemm_f32out_bias(
    const bf16* __restrict__ A, const bf16* __restrict__ Bt,
    float* __restrict__ C, const float* __restrict__ bias, int K, int N) {
  const int i = blockIdx.x;
  const int local = i >> 3;
  const int tm = ((i & 7) * 8 + local / 5) * 256;
  const int tn = (local % 5) * 256;
  gemm256_core<false, true>(A, Bt, C, bias, K, N, tm, tn, 1 << 30);
}

// ---------------- fused dual cross-attention (unchanged) ----------------
__global__ __launch_bounds__(256) void attention_kernel(
    const bf16* __restrict__ q, const bf16* __restrict__ k,
    const bf16* __restrict__ v, const bf16* __restrict__ ipk,
    const bf16* __restrict__ ipv, bf16* __restrict__ out) {
  __shared__ bf16 Kl[96 * 64];
  __shared__ bf16 Vt[64 * 104];
  __shared__ bf16 Pl[4][16 * 104];

  const int b = blockIdx.z, h = blockIdx.y, qblk = blockIdx.x;
  const int tid = threadIdx.x;

  {
    uint32_t* vz = (uint32_t*)Vt;
    for (int i = tid; i < 64 * 104 / 2; i += 256) vz[i] = 0;
  }
  __syncthreads();

  for (int c = tid; c < 77 * 8; c += 256) {
    const int row = c >> 3, d0 = (c & 7) * 8;
    const long src = (long)(b * 77 + row) * 1280 + h * 64 + d0;
    bf16x8 kk = *(const bf16x8*)&k[src];
    *(bf16x8*)&Kl[row * 64 + (d0 ^ ((row & 7) << 3))] = kk;
    bf16x8 vv = *(const bf16x8*)&v[src];
#pragma unroll
    for (int i2 = 0; i2 < 8; i2++) Vt[(d0 + i2) * 104 + row] = vv[i2];
  }
  if (tid < 16 * 8) {
    const int r = tid >> 3, d0 = (tid & 7) * 8;
    const int row = 80 + r;
    const long src = (long)(b * 16 + r) * 1280 + h * 64 + d0;
    bf16x8 kk = *(const bf16x8*)&ipk[src];
    *(bf16x8*)&Kl[row * 64 + (d0 ^ ((row & 7) << 3))] = kk;
    bf16x8 vv = *(const bf16x8*)&ipv[src];
#pragma unroll
    for (int i2 = 0; i2 < 8; i2++) Vt[(d0 + i2) * 104 + row] = vv[i2];
  }
  __syncthreads();

  const int wave = tid >> 6, lane = tid & 63;
  const int g = lane >> 4, l16 = lane & 15;
  const float sc = 0.125f * 1.44269504f;  // 1/sqrt(64) * log2(e)

  for (int it = 0; it < 2; it++) {
    const long qrow = (long)b * 4096 + qblk * 128 + wave * 32 + it * 16;
    bf16x8 qf[2];
#pragma unroll
    for (int ks = 0; ks < 2; ks++)
      qf[ks] = *(const bf16x8*)&q[(qrow + l16) * 1280 + h * 64 + ks * 32 + g * 8];

    f32x4 lt[6];
#pragma unroll
    for (int t = 0; t < 6; t++) {
      f32x4 a = {0.f, 0.f, 0.f, 0.f};
#pragma unroll
      for (int ks = 0; ks < 2; ks++) {
        const int row = t * 16 + l16;
        const int d = (ks * 32 + g * 8) ^ ((row & 7) << 3);
        bf16x8 kb8 = *(const bf16x8*)&Kl[row * 64 + d];
        a = MFMA16(qf[ks], kb8, a);
      }
      lt[t] = a;
    }

    float p[6][4];
#pragma unroll
    for (int r = 0; r < 4; r++) {
      float lv[5], m = -3e38f;
#pragma unroll
      for (int t = 0; t < 5; t++) {
        const int kv = t * 16 + l16;
        lv[t] = (kv < 77) ? lt[t][r] * sc : -3e38f;
        m = fmaxf(m, lv[t]);
      }
      for (int msk = 1; msk < 16; msk <<= 1) m = fmaxf(m, __shfl_xor(m, msk, 16));
      float s = 0.f;
#pragma unroll
      for (int t = 0; t < 5; t++) {
        const float pp = exp2f(lv[t] - m);
        p[t][r] = pp;
        s += pp;
      }
      for (int msk = 1; msk < 16; msk <<= 1) s += __shfl_xor(s, msk, 16);
      const float inv = 1.f / s;
#pragma unroll
      for (int t = 0; t < 5; t++) p[t][r] *= inv;
      const float l5 = lt[5][r] * sc;
      float m2 = l5;
      for (int msk = 1; msk < 16; msk <<= 1) m2 = fmaxf(m2, __shfl_xor(m2, msk, 16));
      const float p5 = exp2f(l5 - m2);
      float s2 = p5;
      for (int msk = 1; msk < 16; msk <<= 1) s2 += __shfl_xor(s2, msk, 16);
      p[5][r] = p5 / s2;
    }

#pragma unroll
    for (int t = 0; t < 6; t++)
#pragma unroll
      for (int r = 0; r < 4; r++)
        Pl[wave][(g * 4 + r) * 104 + t * 16 + l16] = (bf16)p[t][r];
    __syncthreads();

    bf16x8 paf[3];
#pragma unroll
    for (int ks = 0; ks < 3; ks++)
      paf[ks] = *(const bf16x8*)&Pl[wave][l16 * 104 + ks * 32 + g * 8];
#pragma unroll
    for (int n = 0; n < 4; n++) {
      f32x4 o = {0.f, 0.f, 0.f, 0.f};
#pragma unroll
      for (int ks = 0; ks < 3; ks++) {
        bf16x8 vbf = *(const bf16x8*)&Vt[(n * 16 + l16) * 104 + ks * 32 + g * 8];
        o = MFMA16(paf[ks], vbf, o);
      }
#pragma unroll
      for (int r = 0; r < 4; r++)
        out[(qrow + g * 4 + r) * 1280 + h * 64 + n * 16 + l16] = (bf16)o[r];
    }
    __syncthreads();
  }
}

// ---------------- host launch ----------------
extern "C" void kernel_launch(void* const* d_in, const int* in_sizes, int n_in,
                              void* d_out, int out_size, void* d_ws,
                              size_t ws_size, hipStream_t stream) {
  const float* x = (const float*)d_in[0];
  const float* ctx = (const float*)d_in[1];
  const float* img = (const float*)d_in[2];
  const float* Wq = (const float*)d_in[3];
  const float* Wk = (const float*)d_in[4];
  const float* Wv = (const float*)d_in[5];
  const float* Wkip = (const float*)d_in[6];
  const float* Wvip = (const float*)d_in[7];
  const float* Wo = (const float*)d_in[8];
  const float* bo = (const float*)d_in[9];
  float* out = (float*)d_out;

  bf16* ws = (bf16*)d_ws;
  size_t o = 0;
  auto alloc = [&](size_t n) { bf16* p = ws + o; o += n; return p; };
  bf16* xattn = alloc(16384L * 1280);  // x_bf16, later reused for attn output
  bf16* qb    = alloc(16384L * 1280);
  bf16* WqT   = alloc(1280L * 1280);
  bf16* WoT   = alloc(1280L * 1280);
  bf16* WkT   = alloc(1280L * 2048);
  bf16* WvT   = alloc(1280L * 2048);
  bf16* WkipT = alloc(1280L * 2048);
  bf16* WvipT = alloc(1280L * 2048);
  bf16* ctxb  = alloc(384L * 2048);   // 308 valid rows; 256-tile overread -> imgb
  bf16* imgb  = alloc(128L * 2048);   // 64 valid rows; overread -> kb
  bf16* kb    = alloc(384L * 1280);   // stores guarded by Mlim=384
  bf16* vb    = alloc(384L * 1280);
  bf16* ipkb  = alloc(128L * 1280);   // stores guarded by Mlim=128
  bf16* ipvb  = alloc(128L * 1280);

  // all prep (6 transposes + 3 casts) in one launch
  prep_all<<<dim3(40, 64, 11), dim3(32, 8), 0, stream>>>(
      Wq, Wo, Wk, Wv, Wkip, Wvip, WqT, WoT, WkT, WvT, WkipT, WvipT, x, xattn,
      ctx, ctxb, img, imgb);

  // small projections (longest blocks) first, then Q-proj supertile
  gemm_qproj_small<<<350, 512, 0, stream>>>(xattn, WqT, qb, ctxb, imgb, WkT,
                                            WvT, WkipT, WvipT, kb, vb, ipkb,
                                            ipvb);

  // fused dual attention -> xattn (reuses x_bf16 buffer)
  attention_kernel<<<dim3(32, 20, 4), 256, 0, stream>>>(qb, kb, vb, ipkb, ipvb,
                                                        xattn);

  // output projection + bias: out = attn @ Wo + bo (f32 out)
  gemm_f32out_bias<<<320, 512, 0, stream>>>(xattn, WoT, out, bo, 1280, 1280);
}